// Round 1
// baseline (810.330 us; speedup 1.0000x reference)
//
#include <hip/hip_runtime.h>
#include <math.h>

#define NB 32
#define DD 2048
#define NH 16
#define NKVH 2
#define DHD 128
#define SPAST 8192
#define NREP 8
#define NCHUNK 16
#define CHUNK 512

// ws layout (float offsets):
// q     : [0, 65536)          [b][h*dh]
// k_new : [65536, 73728)      [b][kvh*dh]
// v_new : [73728, 81920)      [b][kvh*dh]
// attn  : [81920, 147456)     [b][h*dh]
// Opart : [147456, 1196032)   [b][h][chunk][d]   (32*16*16*128 = 1048576)
// Mpart : [1196032, 1204224)  [b][h][chunk]
// Lpart : [1204224, 1212416)  [b][h][chunk]

__global__ __launch_bounds__(256) void zero_kernel(float* ws, float* out) {
    int idx = blockIdx.x * 256 + threadIdx.x;
    if (idx < 81920) ws[idx] = 0.0f;   // q,k,v (atomic targets)
    if (idx < 65536) out[idx] = 0.0f;  // out (atomic target)
}

__device__ inline void resolve_col(int c, const float* Wq, const float* Wk,
                                   const float* Wv, float* q, float* k, float* v,
                                   const float*& w, float*& y, int& n) {
    if (c < 2048)      { w = Wq + c;          y = q + c;          n = 2048; }
    else if (c < 2304) { w = Wk + (c - 2048); y = k + (c - 2048); n = 256;  }
    else               { w = Wv + (c - 2304); y = v + (c - 2304); n = 256;  }
}

// Fused QKV projection. Weights read exactly once.
// grid (5, 32): 512 cols/block (2 per thread), K-chunk 64, all 32 batches.
__global__ __launch_bounds__(256)
void qkv_gemm(const float* __restrict__ X, const float* __restrict__ Wq,
              const float* __restrict__ Wk, const float* __restrict__ Wv,
              float* __restrict__ q, float* __restrict__ k, float* __restrict__ v) {
    int t = threadIdx.x;
    int colbase = blockIdx.x * 512;
    int k0 = blockIdx.y * 64;
    __shared__ __align__(16) float xs[64][36];  // [kk][b], pad 36 vs transpose conflicts
    for (int i = t; i < 2048; i += 256) {
        int kk = i & 63, b = i >> 6;
        xs[kk][b] = X[(size_t)b * DD + k0 + kk];
    }
    __syncthreads();
    int c0 = colbase + t, c1 = colbase + t + 256;
    const float *w0, *w1; float *y0, *y1; int n0, n1;
    resolve_col(c0, Wq, Wk, Wv, q, k, v, w0, y0, n0);
    resolve_col(c1, Wq, Wk, Wv, q, k, v, w1, y1, n1);
    float acc0[32], acc1[32];
    #pragma unroll
    for (int b = 0; b < 32; ++b) { acc0[b] = 0.f; acc1[b] = 0.f; }
    const float* wp0 = w0 + (size_t)k0 * n0;
    const float* wp1 = w1 + (size_t)k0 * n1;
    #pragma unroll 8
    for (int kk = 0; kk < 64; ++kk) {
        float wa = *wp0; wp0 += n0;
        float wb = *wp1; wp1 += n1;
        #pragma unroll
        for (int b4 = 0; b4 < 8; ++b4) {
            float4 x4 = *(const float4*)&xs[kk][b4 * 4];
            acc0[b4*4+0] = fmaf(x4.x, wa, acc0[b4*4+0]);
            acc0[b4*4+1] = fmaf(x4.y, wa, acc0[b4*4+1]);
            acc0[b4*4+2] = fmaf(x4.z, wa, acc0[b4*4+2]);
            acc0[b4*4+3] = fmaf(x4.w, wa, acc0[b4*4+3]);
            acc1[b4*4+0] = fmaf(x4.x, wb, acc1[b4*4+0]);
            acc1[b4*4+1] = fmaf(x4.y, wb, acc1[b4*4+1]);
            acc1[b4*4+2] = fmaf(x4.z, wb, acc1[b4*4+2]);
            acc1[b4*4+3] = fmaf(x4.w, wb, acc1[b4*4+3]);
        }
    }
    #pragma unroll
    for (int b = 0; b < 32; ++b) {
        atomicAdd(&y0[(size_t)b * n0], acc0[b]);
        atomicAdd(&y1[(size_t)b * n1], acc1[b]);
    }
}

// Generic X[32xK] @ W[KxN] += Y, weights read once. grid (N/512, K/64).
__global__ __launch_bounds__(256)
void gemm2(const float* __restrict__ X, const float* __restrict__ W,
           float* __restrict__ Y, int K, int N) {
    int t = threadIdx.x;
    int c0 = blockIdx.x * 512 + t, c1 = c0 + 256;
    int k0 = blockIdx.y * 64;
    __shared__ __align__(16) float xs[64][36];
    for (int i = t; i < 2048; i += 256) {
        int kk = i & 63, b = i >> 6;
        xs[kk][b] = X[(size_t)b * K + k0 + kk];
    }
    __syncthreads();
    float acc0[32], acc1[32];
    #pragma unroll
    for (int b = 0; b < 32; ++b) { acc0[b] = 0.f; acc1[b] = 0.f; }
    const float* wp0 = W + (size_t)k0 * N + c0;
    const float* wp1 = W + (size_t)k0 * N + c1;
    #pragma unroll 8
    for (int kk = 0; kk < 64; ++kk) {
        float wa = *wp0; wp0 += N;
        float wb = *wp1; wp1 += N;
        #pragma unroll
        for (int b4 = 0; b4 < 8; ++b4) {
            float4 x4 = *(const float4*)&xs[kk][b4 * 4];
            acc0[b4*4+0] = fmaf(x4.x, wa, acc0[b4*4+0]);
            acc0[b4*4+1] = fmaf(x4.y, wa, acc0[b4*4+1]);
            acc0[b4*4+2] = fmaf(x4.z, wa, acc0[b4*4+2]);
            acc0[b4*4+3] = fmaf(x4.w, wa, acc0[b4*4+3]);
            acc1[b4*4+0] = fmaf(x4.x, wb, acc1[b4*4+0]);
            acc1[b4*4+1] = fmaf(x4.y, wb, acc1[b4*4+1]);
            acc1[b4*4+2] = fmaf(x4.z, wb, acc1[b4*4+2]);
            acc1[b4*4+3] = fmaf(x4.w, wb, acc1[b4*4+3]);
        }
    }
    #pragma unroll
    for (int b = 0; b < 32; ++b) {
        atomicAdd(&Y[(size_t)b * N + c0], acc0[b]);
        atomicAdd(&Y[(size_t)b * N + c1], acc1[b]);
    }
}

// bias add + RoPE for q,k; bias add for v. One thread per (d, d+64) pair.
__global__ __launch_bounds__(256)
void bias_rope(float* __restrict__ q, float* __restrict__ k, float* __restrict__ v,
               const float* __restrict__ bq, const float* __restrict__ bk,
               const float* __restrict__ bv,
               const float* __restrict__ cosp, const float* __restrict__ sinp) {
    int idx = blockIdx.x * 256 + threadIdx.x;
    if (idx < 32768) {                       // q: 32*16*64 pairs
        int dp = idx & 63;
        int h  = (idx >> 6) & 15;
        int b  = idx >> 10;
        float* qp = q + (size_t)(b * NH + h) * DHD;
        float c0 = cosp[b * DHD + dp],      s0 = sinp[b * DHD + dp];
        float c1 = cosp[b * DHD + dp + 64], s1 = sinp[b * DHD + dp + 64];
        float x0 = qp[dp]      + bq[h * DHD + dp];
        float x1 = qp[dp + 64] + bq[h * DHD + dp + 64];
        qp[dp]      = x0 * c0 - x1 * s0;
        qp[dp + 64] = x1 * c1 + x0 * s1;
    } else if (idx < 32768 + 4096) {         // k: 32*2*64 pairs
        int t  = idx - 32768;
        int dp = t & 63;
        int kh = (t >> 6) & 1;
        int b  = t >> 7;
        float* kp = k + (size_t)(b * NKVH + kh) * DHD;
        float c0 = cosp[b * DHD + dp],      s0 = sinp[b * DHD + dp];
        float c1 = cosp[b * DHD + dp + 64], s1 = sinp[b * DHD + dp + 64];
        float x0 = kp[dp]      + bk[kh * DHD + dp];
        float x1 = kp[dp + 64] + bk[kh * DHD + dp + 64];
        kp[dp]      = x0 * c0 - x1 * s0;
        kp[dp + 64] = x1 * c1 + x0 * s1;
    } else if (idx < 32768 + 4096 + 8192) {  // v bias: 32*2*128
        int t  = idx - 36864;
        int d  = t & 127;
        int kh = (t >> 7) & 1;
        int b  = t >> 8;
        v[(size_t)(b * NKVH + kh) * DHD + d] += bv[kh * DHD + d];
    }
}

// Flash decode v3.
// grid (64, 16 chunks of 512 keys), block 256 (4 waves) -> 1024 blocks = 4/CU.
// Phase 1: lane-per-key scores (2 keys/thread), q broadcast from LDS.
// Phase 2: thread = (sub=t>>5, quad=t&31); sub-group s handles keys kk==s (mod 8)
//          and accumulates ALL 8 heads per V load -> V read once per block,
//          fully coalesced (1 KB/wave-load), 8x fewer VMEM instrs than v2.
//          Cross-sub reduce: shfl_xor(32) pair-reduce, then 16 KB LDS tree
//          overlaid on ptile (dead after barrier). LDS ~21 KB total.
__global__ __launch_bounds__(256)
void attn_decode(const float* __restrict__ pastK, const float* __restrict__ pastV,
                 const float* __restrict__ qbuf, const float* __restrict__ knew,
                 const float* __restrict__ vnew,
                 float* __restrict__ Opart, float* __restrict__ Mpart,
                 float* __restrict__ Lpart) {
    int b    = blockIdx.x >> 1;
    int kvh  = blockIdx.x & 1;
    int c    = blockIdx.y;
    int t    = threadIdx.x;
    int lane = t & 63;
    int wid  = t >> 6;
    const float scaling = 0.08838834764831845f;  // 128^-0.5

    __shared__ __align__(16) float qs[NREP][DHD];          // 4 KB
    __shared__ __align__(16) float ptile[NREP][CHUNK + 8]; // 16.6 KB (slot 512 = new key); reused as red
    __shared__ float redm[4][NREP], redl[4][NREP];
    __shared__ float snew_s[NREP];

    for (int i = t; i < NREP * DHD; i += 256) {
        int h = i >> 7, d = i & 127;
        qs[h][d] = qbuf[((size_t)(b * NH) + kvh * NREP + h) * DHD + d] * scaling;
    }
    __syncthreads();

    // ---- Phase 1: scores. Thread t owns keys c*512 + t and c*512 + t + 256.
    const float* Kbase = pastK + ((size_t)(b * NKVH) + kvh) * SPAST * DHD;
    const float4* kp0 = (const float4*)(Kbase + (size_t)(c * CHUNK + t) * DHD);
    const float4* kp1 = (const float4*)(Kbase + (size_t)(c * CHUNK + t + 256) * DHD);
    float s0[8], s1[8];
    #pragma unroll
    for (int h = 0; h < 8; ++h) { s0[h] = 0.f; s1[h] = 0.f; }

    #pragma unroll 4
    for (int c4 = 0; c4 < 32; ++c4) {
        float4 kr0 = kp0[c4];
        float4 kr1 = kp1[c4];
        #pragma unroll
        for (int h = 0; h < 8; ++h) {
            float4 q4 = *(const float4*)&qs[h][c4 * 4];
            s0[h] = fmaf(q4.x, kr0.x, s0[h]);
            s0[h] = fmaf(q4.y, kr0.y, s0[h]);
            s0[h] = fmaf(q4.z, kr0.z, s0[h]);
            s0[h] = fmaf(q4.w, kr0.w, s0[h]);
            s1[h] = fmaf(q4.x, kr1.x, s1[h]);
            s1[h] = fmaf(q4.y, kr1.y, s1[h]);
            s1[h] = fmaf(q4.z, kr1.z, s1[h]);
            s1[h] = fmaf(q4.w, kr1.w, s1[h]);
        }
    }

    // new key (position 8192): only last chunk, computed by threads 0..7
    if (c == NCHUNK - 1 && t < 8) {
        const float4* kn = (const float4*)(knew + (size_t)(b * NKVH + kvh) * DHD);
        float sa = 0.f;
        for (int c4 = 0; c4 < 32; ++c4) {
            float4 q4 = *(const float4*)&qs[t][c4 * 4];
            float4 k4 = kn[c4];
            sa += q4.x * k4.x + q4.y * k4.y + q4.z * k4.z + q4.w * k4.w;
        }
        snew_s[t] = sa;
    }

    // per-head max: thread-local -> wave shuffle -> LDS cross-wave
    float mm[8];
    #pragma unroll
    for (int h = 0; h < 8; ++h) mm[h] = fmaxf(s0[h], s1[h]);
    #pragma unroll
    for (int off = 32; off >= 1; off >>= 1)
        #pragma unroll
        for (int h = 0; h < 8; ++h) mm[h] = fmaxf(mm[h], __shfl_xor(mm[h], off));
    if (lane == 0)
        #pragma unroll
        for (int h = 0; h < 8; ++h) redm[wid][h] = mm[h];
    __syncthreads();

    float m[8];
    #pragma unroll
    for (int h = 0; h < 8; ++h) {
        m[h] = fmaxf(fmaxf(redm[0][h], redm[1][h]), fmaxf(redm[2][h], redm[3][h]));
        if (c == NCHUNK - 1) m[h] = fmaxf(m[h], snew_s[h]);
    }

    // p = exp(s - m), write to ptile, accumulate l
    float ll[8];
    #pragma unroll
    for (int h = 0; h < 8; ++h) {
        float p0 = __expf(s0[h] - m[h]);
        float p1 = __expf(s1[h] - m[h]);
        ptile[h][t]       = p0;
        ptile[h][t + 256] = p1;
        ll[h] = p0 + p1;
    }
    #pragma unroll
    for (int off = 32; off >= 1; off >>= 1)
        #pragma unroll
        for (int h = 0; h < 8; ++h) ll[h] += __shfl_xor(ll[h], off);
    if (lane == 0)
        #pragma unroll
        for (int h = 0; h < 8; ++h) redl[wid][h] = ll[h];
    __syncthreads();

    if (t < 8) {
        int h = t;
        float L = redl[0][h] + redl[1][h] + redl[2][h] + redl[3][h];
        if (c == NCHUNK - 1) {
            float pn = __expf(snew_s[h] - m[h]);
            ptile[h][CHUNK] = pn;
            L += pn;
        }
        int gh = kvh * NREP + h;
        Mpart[(b * NH + gh) * NCHUNK + c] = m[h];
        Lpart[(b * NH + gh) * NCHUNK + c] = L;
    }
    __syncthreads();

    // ---- Phase 2: P*V. thread = (sub = t>>5, quad = t&31).
    // sub-group s handles keys kk = s + 8*i; all 8 heads per load.
    int sub  = t >> 5;
    int quad = t & 31;
    const float* Vrow0 = pastV + (((size_t)(b * NKVH) + kvh) * SPAST + (size_t)c * CHUNK) * DHD;
    float4 acc[8];
    #pragma unroll
    for (int h = 0; h < 8; ++h) acc[h] = make_float4(0.f, 0.f, 0.f, 0.f);

    #pragma unroll 4
    for (int i = 0; i < CHUNK / 8; ++i) {
        int kk = sub + 8 * i;
        float4 v4 = *(const float4*)(Vrow0 + (size_t)kk * DHD + quad * 4);
        #pragma unroll
        for (int h = 0; h < 8; ++h) {
            float p = ptile[h][kk];
            acc[h].x = fmaf(p, v4.x, acc[h].x);
            acc[h].y = fmaf(p, v4.y, acc[h].y);
            acc[h].z = fmaf(p, v4.z, acc[h].z);
            acc[h].w = fmaf(p, v4.w, acc[h].w);
        }
    }
    if (c == NCHUNK - 1 && sub == 0) {  // new key slot (index CHUNK), kk%8 == 0 group
        float4 v4 = *(const float4*)(vnew + (size_t)(b * NKVH + kvh) * DHD + quad * 4);
        #pragma unroll
        for (int h = 0; h < 8; ++h) {
            float p = ptile[h][CHUNK];
            acc[h].x = fmaf(p, v4.x, acc[h].x);
            acc[h].y = fmaf(p, v4.y, acc[h].y);
            acc[h].z = fmaf(p, v4.z, acc[h].z);
            acc[h].w = fmaf(p, v4.w, acc[h].w);
        }
    }

    // pair-reduce subs within wave: lanes l and l^32 are (sub 2w, sub 2w+1), same quad
    #pragma unroll
    for (int h = 0; h < 8; ++h) {
        acc[h].x += __shfl_xor(acc[h].x, 32);
        acc[h].y += __shfl_xor(acc[h].y, 32);
        acc[h].z += __shfl_xor(acc[h].z, 32);
        acc[h].w += __shfl_xor(acc[h].w, 32);
    }
    __syncthreads();           // all ptile reads complete -> safe to overlay
    float* red = &ptile[0][0]; // red[w][h][128] = 4096 floats, fits in ptile (4160)
    if (lane < 32) {
        #pragma unroll
        for (int h = 0; h < 8; ++h)
            *(float4*)&red[(size_t)(wid * 8 + h) * 128 + lane * 4] = acc[h];
    }
    __syncthreads();

    // final cross-wave sum + store: thread = (h2 = t>>5, quad)
    int h2 = t >> 5;
    float4 o = make_float4(0.f, 0.f, 0.f, 0.f);
    #pragma unroll
    for (int w = 0; w < 4; ++w) {
        float4 a = *(const float4*)&red[(size_t)(w * 8 + h2) * 128 + quad * 4];
        o.x += a.x; o.y += a.y; o.z += a.z; o.w += a.w;
    }
    int gh = kvh * NREP + h2;
    float* op = Opart + ((size_t)(b * NH + gh) * NCHUNK + c) * DHD;
    *(float4*)(op + quad * 4) = o;
}

__global__ __launch_bounds__(256)
void attn_combine(const float* __restrict__ Opart, const float* __restrict__ Mpart,
                  const float* __restrict__ Lpart, float* __restrict__ attn) {
    int idx  = blockIdx.x * 256 + threadIdx.x;  // 32*16*32 = 16384
    int quad = idx & 31;
    int bh   = idx >> 5;
    float mstar = -1e30f;
    #pragma unroll
    for (int cg = 0; cg < NCHUNK; ++cg) mstar = fmaxf(mstar, Mpart[bh * NCHUNK + cg]);
    float  L = 0.f;
    float4 O = make_float4(0.f, 0.f, 0.f, 0.f);
    #pragma unroll
    for (int cg = 0; cg < NCHUNK; ++cg) {
        float f = __expf(Mpart[bh * NCHUNK + cg] - mstar);
        L += f * Lpart[bh * NCHUNK + cg];
        const float4* ap = (const float4*)(Opart + ((size_t)bh * NCHUNK + cg) * DHD);
        float4 a = ap[quad];
        O.x += f * a.x; O.y += f * a.y; O.z += f * a.z; O.w += f * a.w;
    }
    float inv = 1.0f / L;
    float4* outp = (float4*)(attn + (size_t)bh * DHD);
    outp[quad] = make_float4(O.x * inv, O.y * inv, O.z * inv, O.w * inv);
}

extern "C" void kernel_launch(void* const* d_in, const int* in_sizes, int n_in,
                              void* d_out, int out_size, void* d_ws, size_t ws_size,
                              hipStream_t stream) {
    const float* hs    = (const float*)d_in[0];
    const float* cosp  = (const float*)d_in[1];
    const float* sinp  = (const float*)d_in[2];
    const float* pastK = (const float*)d_in[3];
    const float* pastV = (const float*)d_in[4];
    const float* Wq    = (const float*)d_in[5];
    const float* bq    = (const float*)d_in[6];
    const float* Wk    = (const float*)d_in[7];
    const float* bk    = (const float*)d_in[8];
    const float* Wv    = (const float*)d_in[9];
    const float* bv    = (const float*)d_in[10];
    const float* Wo    = (const float*)d_in[11];
    float* out = (float*)d_out;
    float* ws  = (float*)d_ws;

    float* q     = ws;
    float* k     = ws + 65536;
    float* v     = ws + 73728;
    float* attn  = ws + 81920;
    float* Opart = ws + 147456;
    float* Mpart = ws + 1196032;
    float* Lpart = ws + 1204224;

    zero_kernel<<<320, 256, 0, stream>>>(ws, out);
    qkv_gemm<<<dim3(5, 32), 256, 0, stream>>>(hs, Wq, Wk, Wv, q, k, v);
    bias_rope<<<176, 256, 0, stream>>>(q, k, v, bq, bk, bv, cosp, sinp);
    attn_decode<<<dim3(64, NCHUNK), 256, 0, stream>>>(pastK, pastV, q, k, v,
                                                      Opart, Mpart, Lpart);
    attn_combine<<<64, 256, 0, stream>>>(Opart, Mpart, Lpart, attn);
    gemm2<<<dim3(4, 32), 256, 0, stream>>>(attn, Wo, out, DD, DD);
}

// Round 2
// 690.006 us; speedup vs baseline: 1.1744x; 1.1744x over previous
//
#include <hip/hip_runtime.h>
#include <math.h>

#define NB 32
#define DD 2048
#define NH 16
#define NKVH 2
#define DHD 128
#define SPAST 8192
#define NREP 8
#define NCHUNK 16
#define CHUNK 512
#define TK 32
#define NTILE (CHUNK / TK)   // 16

// ws layout (float offsets):
// q     : [0, 65536)          [b][h*dh]
// k_new : [65536, 73728)      [b][kvh*dh]
// v_new : [73728, 81920)      [b][kvh*dh]
// attn  : [81920, 147456)     [b][h*dh]
// Opart : [147456, 1196032)   [b][h][chunk][d]   (32*16*16*128 = 1048576)
// Mpart : [1196032, 1204224)  [b][h][chunk]
// Lpart : [1204224, 1212416)  [b][h][chunk]

__global__ __launch_bounds__(256) void zero_kernel(float* ws, float* out) {
    int idx = blockIdx.x * 256 + threadIdx.x;
    if (idx < 81920) ws[idx] = 0.0f;   // q,k,v (atomic targets)
    if (idx < 65536) out[idx] = 0.0f;  // out (atomic target)
}

__device__ inline void resolve_col(int c, const float* Wq, const float* Wk,
                                   const float* Wv, float* q, float* k, float* v,
                                   const float*& w, float*& y, int& n) {
    if (c < 2048)      { w = Wq + c;          y = q + c;          n = 2048; }
    else if (c < 2304) { w = Wk + (c - 2048); y = k + (c - 2048); n = 256;  }
    else               { w = Wv + (c - 2304); y = v + (c - 2304); n = 256;  }
}

// Fused QKV projection. Weights read exactly once.
// grid (5, 64): 512 cols/block (2 per thread), K-chunk 32, all 32 batches.
__global__ __launch_bounds__(256)
void qkv_gemm(const float* __restrict__ X, const float* __restrict__ Wq,
              const float* __restrict__ Wk, const float* __restrict__ Wv,
              float* __restrict__ q, float* __restrict__ k, float* __restrict__ v) {
    int t = threadIdx.x;
    int colbase = blockIdx.x * 512;
    int k0 = blockIdx.y * 32;
    __shared__ __align__(16) float xs[32][36];  // [kk][b], pad 36 vs transpose conflicts
    for (int i = t; i < 1024; i += 256) {
        int kk = i & 31, b = i >> 5;
        xs[kk][b] = X[(size_t)b * DD + k0 + kk];
    }
    __syncthreads();
    int c0 = colbase + t, c1 = colbase + t + 256;
    const float *w0, *w1; float *y0, *y1; int n0, n1;
    resolve_col(c0, Wq, Wk, Wv, q, k, v, w0, y0, n0);
    resolve_col(c1, Wq, Wk, Wv, q, k, v, w1, y1, n1);
    float acc0[32], acc1[32];
    #pragma unroll
    for (int b = 0; b < 32; ++b) { acc0[b] = 0.f; acc1[b] = 0.f; }
    const float* wp0 = w0 + (size_t)k0 * n0;
    const float* wp1 = w1 + (size_t)k0 * n1;
    #pragma unroll 8
    for (int kk = 0; kk < 32; ++kk) {
        float wa = *wp0; wp0 += n0;
        float wb = *wp1; wp1 += n1;
        #pragma unroll
        for (int b4 = 0; b4 < 8; ++b4) {
            float4 x4 = *(const float4*)&xs[kk][b4 * 4];
            acc0[b4*4+0] = fmaf(x4.x, wa, acc0[b4*4+0]);
            acc0[b4*4+1] = fmaf(x4.y, wa, acc0[b4*4+1]);
            acc0[b4*4+2] = fmaf(x4.z, wa, acc0[b4*4+2]);
            acc0[b4*4+3] = fmaf(x4.w, wa, acc0[b4*4+3]);
            acc1[b4*4+0] = fmaf(x4.x, wb, acc1[b4*4+0]);
            acc1[b4*4+1] = fmaf(x4.y, wb, acc1[b4*4+1]);
            acc1[b4*4+2] = fmaf(x4.z, wb, acc1[b4*4+2]);
            acc1[b4*4+3] = fmaf(x4.w, wb, acc1[b4*4+3]);
        }
    }
    #pragma unroll
    for (int b = 0; b < 32; ++b) {
        atomicAdd(&y0[(size_t)b * n0], acc0[b]);
        atomicAdd(&y1[(size_t)b * n1], acc1[b]);
    }
}

// Generic X[32xK] @ W[KxN] += Y, weights read once. grid (N/512, K/32).
__global__ __launch_bounds__(256)
void gemm2(const float* __restrict__ X, const float* __restrict__ W,
           float* __restrict__ Y, int K, int N) {
    int t = threadIdx.x;
    int c0 = blockIdx.x * 512 + t, c1 = c0 + 256;
    int k0 = blockIdx.y * 32;
    __shared__ __align__(16) float xs[32][36];
    for (int i = t; i < 1024; i += 256) {
        int kk = i & 31, b = i >> 5;
        xs[kk][b] = X[(size_t)b * K + k0 + kk];
    }
    __syncthreads();
    float acc0[32], acc1[32];
    #pragma unroll
    for (int b = 0; b < 32; ++b) { acc0[b] = 0.f; acc1[b] = 0.f; }
    const float* wp0 = W + (size_t)k0 * N + c0;
    const float* wp1 = W + (size_t)k0 * N + c1;
    #pragma unroll 8
    for (int kk = 0; kk < 32; ++kk) {
        float wa = *wp0; wp0 += N;
        float wb = *wp1; wp1 += N;
        #pragma unroll
        for (int b4 = 0; b4 < 8; ++b4) {
            float4 x4 = *(const float4*)&xs[kk][b4 * 4];
            acc0[b4*4+0] = fmaf(x4.x, wa, acc0[b4*4+0]);
            acc0[b4*4+1] = fmaf(x4.y, wa, acc0[b4*4+1]);
            acc0[b4*4+2] = fmaf(x4.z, wa, acc0[b4*4+2]);
            acc0[b4*4+3] = fmaf(x4.w, wa, acc0[b4*4+3]);
            acc1[b4*4+0] = fmaf(x4.x, wb, acc1[b4*4+0]);
            acc1[b4*4+1] = fmaf(x4.y, wb, acc1[b4*4+1]);
            acc1[b4*4+2] = fmaf(x4.z, wb, acc1[b4*4+2]);
            acc1[b4*4+3] = fmaf(x4.w, wb, acc1[b4*4+3]);
        }
    }
    #pragma unroll
    for (int b = 0; b < 32; ++b) {
        atomicAdd(&Y[(size_t)b * N + c0], acc0[b]);
        atomicAdd(&Y[(size_t)b * N + c1], acc1[b]);
    }
}

// bias add + RoPE for q,k; bias add for v. One thread per (d, d+64) pair.
__global__ __launch_bounds__(256)
void bias_rope(float* __restrict__ q, float* __restrict__ k, float* __restrict__ v,
               const float* __restrict__ bq, const float* __restrict__ bk,
               const float* __restrict__ bv,
               const float* __restrict__ cosp, const float* __restrict__ sinp) {
    int idx = blockIdx.x * 256 + threadIdx.x;
    if (idx < 32768) {                       // q: 32*16*64 pairs
        int dp = idx & 63;
        int h  = (idx >> 6) & 15;
        int b  = idx >> 10;
        float* qp = q + (size_t)(b * NH + h) * DHD;
        float c0 = cosp[b * DHD + dp],      s0 = sinp[b * DHD + dp];
        float c1 = cosp[b * DHD + dp + 64], s1 = sinp[b * DHD + dp + 64];
        float x0 = qp[dp]      + bq[h * DHD + dp];
        float x1 = qp[dp + 64] + bq[h * DHD + dp + 64];
        qp[dp]      = x0 * c0 - x1 * s0;
        qp[dp + 64] = x1 * c1 + x0 * s1;
    } else if (idx < 32768 + 4096) {         // k: 32*2*64 pairs
        int t  = idx - 32768;
        int dp = t & 63;
        int kh = (t >> 6) & 1;
        int b  = t >> 7;
        float* kp = k + (size_t)(b * NKVH + kh) * DHD;
        float c0 = cosp[b * DHD + dp],      s0 = sinp[b * DHD + dp];
        float c1 = cosp[b * DHD + dp + 64], s1 = sinp[b * DHD + dp + 64];
        float x0 = kp[dp]      + bk[kh * DHD + dp];
        float x1 = kp[dp + 64] + bk[kh * DHD + dp + 64];
        kp[dp]      = x0 * c0 - x1 * s0;
        kp[dp + 64] = x1 * c1 + x0 * s1;
    } else if (idx < 32768 + 4096 + 8192) {  // v bias: 32*2*128
        int t  = idx - 36864;
        int d  = t & 127;
        int kh = (t >> 7) & 1;
        int b  = t >> 8;
        v[(size_t)(b * NKVH + kh) * DHD + d] += bv[kh * DHD + d];
    }
}

// Flash decode v4: fetch-clean access patterns + half-wave-local softmax.
// grid (64, 16 chunks of 512 keys), block 256 (4 waves).
// Per 32-row K tile: reg-prefetched coalesced stage -> XOR-swizzled LDS;
// thread = (row r=t&31, head h=t>>5): head lives in one 32-lane half-wave,
// so softmax max/sum are 5x shfl_xor, m/L/O-scale all in registers.
// PV: thread = (head h, quad r); 8 head-groups read the same sequential V row
// (one HBM fetch, 7 L1 hits). Only 2 barriers per tile (LDS staging handoff).
__global__ __launch_bounds__(256)
void attn_decode(const float* __restrict__ pastK, const float* __restrict__ pastV,
                 const float* __restrict__ qbuf, const float* __restrict__ knew,
                 const float* __restrict__ vnew,
                 float* __restrict__ Opart, float* __restrict__ Mpart,
                 float* __restrict__ Lpart) {
    int b   = blockIdx.x >> 1;
    int kvh = blockIdx.x & 1;
    int c   = blockIdx.y;
    int t   = threadIdx.x;
    const float scaling = 0.08838834764831845f;  // 128^-0.5

    __shared__ __align__(16) float ks[TK][DHD];    // 16 KB, columns XOR-swizzled by row
    __shared__ __align__(16) float qs[NREP][DHD];  // 4 KB
    __shared__ float ptileT[NREP][TK];             // 1 KB

    for (int i = t; i < NREP * DHD; i += 256) {
        qs[i >> 7][i & 127] =
            qbuf[((size_t)(b * NH) + kvh * NREP + (i >> 7)) * DHD + (i & 127)] * scaling;
    }

    const float* Kc = pastK + (((size_t)(b * NKVH) + kvh) * SPAST + (size_t)c * CHUNK) * DHD;
    const float* Vc = pastV + (((size_t)(b * NKVH) + kvh) * SPAST + (size_t)c * CHUNK) * DHD;

    int h = t >> 5;   // head 0..7 (half-wave-local)
    int r = t & 31;   // score row within tile; also PV dim-quad
    const float4* qs4 = (const float4*)&qs[h][0];

    // prefetch tile 0 into regs (coalesced: wave covers contiguous 1 KB per pass)
    float4 kst[4];
    #pragma unroll
    for (int p = 0; p < 4; ++p) {
        int f  = p * 256 + t;
        int rr = f >> 5, cc = f & 31;
        kst[p] = *(const float4*)(Kc + (size_t)rr * DHD + cc * 4);
    }

    float m_run = -1e30f, L_run = 0.f;
    float4 O4 = make_float4(0.f, 0.f, 0.f, 0.f);

    __syncthreads();  // qs ready

    for (int j = 0; j < NTILE; ++j) {
        // write staged tile j to LDS, XOR-swizzled column (conflict-free writes)
        #pragma unroll
        for (int p = 0; p < 4; ++p) {
            int f  = p * 256 + t;
            int rr = f >> 5, cc = f & 31;
            *(float4*)&ks[rr][(cc ^ (rr & 7)) << 2] = kst[p];
        }
        __syncthreads();  // (A) tile j visible; everyone past last tile's reads

        // prefetch tile j+1 (in flight under score+softmax+PV; written next iter)
        if (j + 1 < NTILE) {
            const float* Kn = Kc + (size_t)(j + 1) * TK * DHD;
            #pragma unroll
            for (int p = 0; p < 4; ++p) {
                int f  = p * 256 + t;
                int rr = f >> 5, cc = f & 31;
                kst[p] = *(const float4*)(Kn + (size_t)rr * DHD + cc * 4);
            }
        }

        // scores: s = q[h] . K[r]  (swizzled LDS read: banks spread over r&7)
        float s = 0.f;
        const float4* krow = (const float4*)&ks[r][0];
        int sw = r & 7;
        #pragma unroll 8
        for (int d4 = 0; d4 < 32; ++d4) {
            float4 kv = krow[d4 ^ sw];
            float4 q4 = qs4[d4];
            s = fmaf(kv.x, q4.x, s);
            s = fmaf(kv.y, q4.y, s);
            s = fmaf(kv.z, q4.z, s);
            s = fmaf(kv.w, q4.w, s);
        }
        __syncthreads();  // (D) all score reads of tile j done -> next write safe

        // half-wave softmax (head h entirely within its 32 lanes)
        float tmax = s;
        #pragma unroll
        for (int off = 16; off >= 1; off >>= 1)
            tmax = fmaxf(tmax, __shfl_xor(tmax, off));
        float nm    = fmaxf(m_run, tmax);
        float scale = __expf(m_run - nm);
        m_run = nm;
        float p = __expf(s - nm);
        ptileT[h][r] = p;
        float lsum = p;
        #pragma unroll
        for (int off = 16; off >= 1; off >>= 1)
            lsum += __shfl_xor(lsum, off);
        L_run = L_run * scale + lsum;
        O4.x *= scale; O4.y *= scale; O4.z *= scale; O4.w *= scale;

        // PV: thread = (h, quad r); all groups walk the same sequential V rows
        const float* Vt = Vc + (size_t)j * TK * DHD;
        #pragma unroll 8
        for (int kk = 0; kk < TK; ++kk) {
            float pv  = ptileT[h][kk];                       // half-wave broadcast
            float4 v4 = *(const float4*)(Vt + (size_t)kk * DHD + (r << 2));
            O4.x = fmaf(pv, v4.x, O4.x);
            O4.y = fmaf(pv, v4.y, O4.y);
            O4.z = fmaf(pv, v4.z, O4.z);
            O4.w = fmaf(pv, v4.w, O4.w);
        }
    }

    // new key (position 8192): last chunk only; fully in-register per half-wave
    if (c == NCHUNK - 1) {
        const float4* kn4 = (const float4*)(knew + (size_t)(b * NKVH + kvh) * DHD);
        float4 kv = kn4[r];
        float4 q4 = qs4[r];
        float sp = kv.x * q4.x + kv.y * q4.y + kv.z * q4.z + kv.w * q4.w;
        #pragma unroll
        for (int off = 16; off >= 1; off >>= 1)
            sp += __shfl_xor(sp, off);
        float nm    = fmaxf(m_run, sp);
        float scale = __expf(m_run - nm);
        float pn    = __expf(sp - nm);
        m_run = nm;
        L_run = L_run * scale + pn;
        const float4* vn4 = (const float4*)(vnew + (size_t)(b * NKVH + kvh) * DHD);
        float4 v4 = vn4[r];
        O4.x = fmaf(pn, v4.x, O4.x * scale);
        O4.y = fmaf(pn, v4.y, O4.y * scale);
        O4.z = fmaf(pn, v4.z, O4.z * scale);
        O4.w = fmaf(pn, v4.w, O4.w * scale);
    }

    int gh = kvh * NREP + h;
    float* op = Opart + ((size_t)(b * NH + gh) * NCHUNK + c) * DHD;
    *(float4*)(op + (r << 2)) = O4;
    if (r == 0) {
        Mpart[(b * NH + gh) * NCHUNK + c] = m_run;
        Lpart[(b * NH + gh) * NCHUNK + c] = L_run;
    }
}

__global__ __launch_bounds__(256)
void attn_combine(const float* __restrict__ Opart, const float* __restrict__ Mpart,
                  const float* __restrict__ Lpart, float* __restrict__ attn) {
    int idx  = blockIdx.x * 256 + threadIdx.x;  // 32*16*32 = 16384
    int quad = idx & 31;
    int bh   = idx >> 5;
    float mstar = -1e30f;
    #pragma unroll
    for (int cg = 0; cg < NCHUNK; ++cg) mstar = fmaxf(mstar, Mpart[bh * NCHUNK + cg]);
    float  L = 0.f;
    float4 O = make_float4(0.f, 0.f, 0.f, 0.f);
    #pragma unroll
    for (int cg = 0; cg < NCHUNK; ++cg) {
        float f = __expf(Mpart[bh * NCHUNK + cg] - mstar);
        L += f * Lpart[bh * NCHUNK + cg];
        const float4* ap = (const float4*)(Opart + ((size_t)bh * NCHUNK + cg) * DHD);
        float4 a = ap[quad];
        O.x += f * a.x; O.y += f * a.y; O.z += f * a.z; O.w += f * a.w;
    }
    float inv = 1.0f / L;
    float4* outp = (float4*)(attn + (size_t)bh * DHD);
    outp[quad] = make_float4(O.x * inv, O.y * inv, O.z * inv, O.w * inv);
}

extern "C" void kernel_launch(void* const* d_in, const int* in_sizes, int n_in,
                              void* d_out, int out_size, void* d_ws, size_t ws_size,
                              hipStream_t stream) {
    const float* hs    = (const float*)d_in[0];
    const float* cosp  = (const float*)d_in[1];
    const float* sinp  = (const float*)d_in[2];
    const float* pastK = (const float*)d_in[3];
    const float* pastV = (const float*)d_in[4];
    const float* Wq    = (const float*)d_in[5];
    const float* bq    = (const float*)d_in[6];
    const float* Wk    = (const float*)d_in[7];
    const float* bk    = (const float*)d_in[8];
    const float* Wv    = (const float*)d_in[9];
    const float* bv    = (const float*)d_in[10];
    const float* Wo    = (const float*)d_in[11];
    float* out = (float*)d_out;
    float* ws  = (float*)d_ws;

    float* q     = ws;
    float* k     = ws + 65536;
    float* v     = ws + 73728;
    float* attn  = ws + 81920;
    float* Opart = ws + 147456;
    float* Mpart = ws + 1196032;
    float* Lpart = ws + 1204224;

    zero_kernel<<<320, 256, 0, stream>>>(ws, out);
    qkv_gemm<<<dim3(5, 64), 256, 0, stream>>>(hs, Wq, Wk, Wv, q, k, v);
    bias_rope<<<176, 256, 0, stream>>>(q, k, v, bq, bk, bv, cosp, sinp);
    attn_decode<<<dim3(64, NCHUNK), 256, 0, stream>>>(pastK, pastV, q, k, v,
                                                      Opart, Mpart, Lpart);
    attn_combine<<<64, 256, 0, stream>>>(Opart, Mpart, Lpart, attn);
    gemm2<<<dim3(4, 64), 256, 0, stream>>>(attn, Wo, out, DD, DD);
}